// Round 6
// baseline (143.116 us; speedup 1.0000x reference)
//
#include <hip/hip_runtime.h>
#include <hip/hip_cooperative_groups.h>
#include <hip/hip_bf16.h>

namespace cg = cooperative_groups;

#define N_NODES 10000
#define IN_CH 128
#define HID 256
#define E_TAR 8192
#define N_EDGES 320000
#define WPR 320          // bitmask words per row (313 used, padded)
#define MASK_WORDS (N_NODES * WPR)   // 12.8 MB
#define CSR_MAX 128
#define BM 32
#define GRID 256
#define TPB 512

typedef short bf16x8 __attribute__((ext_vector_type(8)));
typedef short bf16x4 __attribute__((ext_vector_type(4)));
typedef float f32x4 __attribute__((ext_vector_type(4)));

__device__ __forceinline__ unsigned short f2bf(float f) {
  union { float f; unsigned u; } v; v.f = f;
  unsigned r = v.u + 0x7fffu + ((v.u >> 16) & 1u);  // RNE
  return (unsigned short)(r >> 16);
}
__device__ __forceinline__ float bf2f(unsigned short h) {
  union { unsigned u; float f; } v; v.u = ((unsigned)h) << 16; return v.f;
}

struct KParams {
  const float* x; const int* tar; const int* adj_r; const int* adj_c;
  const float* beta;
  const float *W1, *b1, *W2, *b2, *W3, *b3;
  const float *Wij1, *bij1, *Wij2, *bij2, *Wl1, *bl1, *Wl2, *bl2;
  unsigned* mask; int* deg; int* csr; unsigned short* wts;
  float* out;
};

template<int KN>
__device__ __forceinline__ void loadB(const unsigned short* __restrict__ Wt,
                                      int wn, int l15, int kg,
                                      bf16x8* b0, bf16x8* b1) {
  const unsigned short* p0 = Wt + (size_t)(wn + l15) * KN + kg;
  const unsigned short* p1 = Wt + (size_t)(wn + 16 + l15) * KN + kg;
  #pragma unroll
  for (int s = 0; s < KN / 32; ++s) {
    b0[s] = *(const bf16x8*)(p0 + s * 32);
    b1[s] = *(const bf16x8*)(p1 + s * 32);
  }
}

template<int K>
__device__ __forceinline__ void computeL(const unsigned short (*A)[264],
                                         const bf16x8* b0, const bf16x8* b1,
                                         int l15, int kg, f32x4 acc[2][2]) {
  #pragma unroll
  for (int s = 0; s < K / 32; ++s) {
    bf16x8 a0 = *(const bf16x8*)&A[l15][s * 32 + kg];
    bf16x8 a1 = *(const bf16x8*)&A[16 + l15][s * 32 + kg];
    acc[0][0] = __builtin_amdgcn_mfma_f32_16x16x32_bf16(a0, b0[s], acc[0][0], 0, 0, 0);
    acc[1][0] = __builtin_amdgcn_mfma_f32_16x16x32_bf16(a1, b0[s], acc[1][0], 0, 0, 0);
    acc[0][1] = __builtin_amdgcn_mfma_f32_16x16x32_bf16(a0, b1[s], acc[0][1], 0, 0, 0);
    acc[1][1] = __builtin_amdgcn_mfma_f32_16x16x32_bf16(a1, b1[s], acc[1][1], 0, 0, 0);
  }
}

__global__ __launch_bounds__(TPB, 2) void fused_pipeline(KParams p) {
  __shared__ unsigned short P[BM][264];
  __shared__ unsigned short Q[BM][264];
  __shared__ float tile[32][33];
  cg::grid_group grid = cg::this_grid();

  int tid = threadIdx.x;
  int lane = tid & 63, wv = tid >> 6;
  int wn = wv * 32;
  int l15 = lane & 15, kg = (lane >> 4) * 8, rq = (lane >> 4) * 4;
  int m0 = blockIdx.x * BM;

  // ---- early prefetch of pure-input data (overlaps phases A/B) ----
  int row = tid >> 4, seg = tid & 15;
  int gi = p.tar[m0 + row], gj = p.tar[E_TAR + m0 + row];
  const float* xip = p.x + (size_t)gi * IN_CH + seg * 8;
  const float* xjp = p.x + (size_t)gj * IN_CH + seg * 8;
  f32x4 xi0 = *(const f32x4*)xip, xi1 = *(const f32x4*)(xip + 4);
  f32x4 xj0 = *(const f32x4*)xjp, xj1 = *(const f32x4*)(xjp + 4);
  float bv1[2]   = { p.b1[wn + l15],   p.b1[wn + 16 + l15] };
  float bv2[2]   = { p.b2[wn + l15],   p.b2[wn + 16 + l15] };
  float bv3[2]   = { p.b3[wn + l15],   p.b3[wn + 16 + l15] };
  float bvij1[2] = { p.bij1[wn + l15], p.bij1[wn + 16 + l15] };
  float bvij2[2] = { p.bij2[wn + l15], p.bij2[wn + 16 + l15] };
  float bvl1[2]  = { p.bl1[wn + l15],  p.bl1[wn + 16 + l15] };
  float beta_v = p.beta[0];
  f32x4 w2v = *(const f32x4*)&p.Wl2[lane * 4];

  // ---- phase A: zero mask+deg; transpose-convert weights ----
  {
    uint4 z = {0u, 0u, 0u, 0u};
    uint4* zp = (uint4*)p.mask;
    const int n4 = (MASK_WORDS + N_NODES) / 4;
    for (int i = blockIdx.x * TPB + tid; i < n4; i += GRID * TPB) zp[i] = z;
  }
  for (int t0 = blockIdx.x; t0 < 320; t0 += GRID) {
    const float* W; unsigned short* O; int K, t;
    if      (t0 <  32) { W = p.W1;   O = p.wts;          K = 128; t = t0; }
    else if (t0 <  96) { W = p.W2;   O = p.wts + 32768;  K = 256; t = t0 - 32; }
    else if (t0 < 160) { W = p.W3;   O = p.wts + 98304;  K = 256; t = t0 - 96; }
    else if (t0 < 192) { W = p.Wij1; O = p.wts + 163840; K = 128; t = t0 - 160; }
    else if (t0 < 256) { W = p.Wij2; O = p.wts + 196608; K = 256; t = t0 - 192; }
    else               { W = p.Wl1;  O = p.wts + 262144; K = 256; t = t0 - 256; }
    int tpk = K / 32, tk = t % tpk, tn = t / tpk;
    int c = tid & 31, r = tid >> 5;        // r in 0..15
    __syncthreads();                        // tile reuse across iterations
    tile[r][c]      = W[(size_t)(tk * 32 + r) * 256 + tn * 32 + c];
    tile[r + 16][c] = W[(size_t)(tk * 32 + r + 16) * 256 + tn * 32 + c];
    __syncthreads();
    O[(size_t)(tn * 32 + r) * K + tk * 32 + c]      = f2bf(tile[c][r]);
    O[(size_t)(tn * 32 + r + 16) * K + tk * 32 + c] = f2bf(tile[c][r + 16]);
  }
  grid.sync();

  // ---- phase B: scatter adjacency bits; 0->1 winners build dedup'd CSR ----
  for (int k = blockIdx.x * TPB + tid; k < N_EDGES; k += GRID * TPB) {
    int r = p.adj_r[k], c = p.adj_c[k];
    unsigned bit = 1u << (c & 31);
    unsigned old = atomicOr(&p.mask[(size_t)r * WPR + (c >> 5)], bit);
    if (!(old & bit)) {
      int q = atomicAdd(&p.deg[r], 1);
      if (q < CSR_MAX) p.csr[(size_t)r * CSR_MAX + q] = c;
    }
  }
  grid.sync();

  // ---- phase C: CN gather + MLP chain + head ----
  bf16x8 B0[8], B1[8];
  loadB<128>(p.wts, wn, l15, kg, B0, B1);   // L1 weights; latency hides under gather

  // batched headers: overlap the 4 edges' pointer-chase
  int ti[4], tj[4], di[4], dj[4];
  #pragma unroll
  for (int q = 0; q < 4; ++q) {
    int e = m0 + wv * 4 + q;
    ti[q] = p.tar[e]; tj[q] = p.tar[E_TAR + e];
  }
  #pragma unroll
  for (int q = 0; q < 4; ++q) { di[q] = p.deg[ti[q]]; dj[q] = p.deg[tj[q]]; }

  float g0[4] = {0.f, 0.f, 0.f, 0.f}, g1[4] = {0.f, 0.f, 0.f, 0.f};
  #pragma unroll
  for (int q = 0; q < 4; ++q) {
    int a  = (di[q] <= dj[q]) ? ti[q] : tj[q];
    int b  = (di[q] <= dj[q]) ? tj[q] : ti[q];
    int da = min(di[q], dj[q]);            // wave-uniform (Binomial(320k,1e-4): max deg << 128)
    const unsigned* mb = p.mask + (size_t)b * WPR;
    const int* la = p.csr + (size_t)a * CSR_MAX;
    int nit = (da + 63) >> 6;              // usually 1
    for (int it = 0; it < nit; ++it) {
      int t = it * 64 + lane;
      int n = 0; bool hit = false;
      if (t < da) {
        n = la[t];
        hit = (mb[n >> 5] >> (n & 31)) & 1u;
      }
      unsigned long long bal = __ballot(hit);
      while (bal) {                        // all 64 lanes accumulate each hit
        int src = __ffsll(bal) - 1;
        bal &= bal - 1;
        int nb = __shfl(n, src);
        const float* xr = p.x + (size_t)nb * IN_CH;
        g0[q] += xr[lane];
        g1[q] += xr[lane + 64];
      }
    }
  }
  __syncthreads();   // protect tile (aliased LDS region is separate; protects P from phase-A? P untouched — safety barrier before P writes while other waves may lag)
  #pragma unroll
  for (int q = 0; q < 4; ++q) {
    int r = wv * 4 + q;
    P[r][lane]      = f2bf(g0[q]);
    P[r][64 + lane] = f2bf(g1[q]);
  }
  __syncthreads();

  f32x4 acc[2][2];
  #define ZACC { acc[0][0]=(f32x4){0,0,0,0}; acc[0][1]=(f32x4){0,0,0,0}; \
                 acc[1][0]=(f32x4){0,0,0,0}; acc[1][1]=(f32x4){0,0,0,0}; }
  #define EPI(dst, bv, RELU) { \
    _Pragma("unroll") for (int nf = 0; nf < 2; ++nf) { \
      int cg = wn + nf * 16 + l15; \
      _Pragma("unroll") for (int m = 0; m < 2; ++m) \
        _Pragma("unroll") for (int i = 0; i < 4; ++i) { \
          float v = acc[m][nf][i] + bv[nf]; \
          if (RELU) v = fmaxf(v, 0.f); \
          dst[m * 16 + rq + i][cg] = f2bf(v); \
        } \
    } }

  // L1: Q = relu(P @ W1 + b1), K=128
  ZACC; computeL<128>(P, B0, B1, l15, kg, acc);
  loadB<256>(p.wts + 32768, wn, l15, kg, B0, B1);
  EPI(Q, bv1, 1);
  __syncthreads();

  // L2: P = relu(Q @ W2 + b2)
  ZACC; computeL<256>(Q, B0, B1, l15, kg, acc);
  loadB<256>(p.wts + 98304, wn, l15, kg, B0, B1);
  EPI(P, bv2, 1);
  __syncthreads();

  // L3: xcn (regs) = P @ W3 + b3
  f32x4 xcn[2][2];
  xcn[0][0]=(f32x4){0,0,0,0}; xcn[0][1]=(f32x4){0,0,0,0};
  xcn[1][0]=(f32x4){0,0,0,0}; xcn[1][1]=(f32x4){0,0,0,0};
  computeL<256>(P, B0, B1, l15, kg, xcn);
  loadB<128>(p.wts + 163840, wn, l15, kg, B0, B1);
  #pragma unroll
  for (int nf = 0; nf < 2; ++nf)
    #pragma unroll
    for (int m = 0; m < 2; ++m)
      #pragma unroll
      for (int i = 0; i < 4; ++i) xcn[m][nf][i] += bv3[nf];
  __syncthreads();   // all P reads done before overwrite

  // gather xi*xj -> P (prefetched at entry)
  {
    unsigned short tmp[8];
    #pragma unroll
    for (int u = 0; u < 4; ++u) {
      tmp[u] = f2bf(xi0[u] * xj0[u]);
      tmp[4 + u] = f2bf(xi1[u] * xj1[u]);
    }
    *(bf16x8*)&P[row][seg * 8] = *(bf16x8*)tmp;
  }
  __syncthreads();

  // L4: Q = relu(P @ Wij1 + bij1), K=128
  ZACC; computeL<128>(P, B0, B1, l15, kg, acc);
  loadB<256>(p.wts + 196608, wn, l15, kg, B0, B1);
  EPI(Q, bvij1, 1);
  __syncthreads();

  // L5: P = (Q @ Wij2 + bij2) + beta*xcn
  ZACC; computeL<256>(Q, B0, B1, l15, kg, acc);
  loadB<256>(p.wts + 262144, wn, l15, kg, B0, B1);
  #pragma unroll
  for (int nf = 0; nf < 2; ++nf) {
    int cg = wn + nf * 16 + l15;
    #pragma unroll
    for (int m = 0; m < 2; ++m)
      #pragma unroll
      for (int i = 0; i < 4; ++i) {
        float v = acc[m][nf][i] + bvij2[nf] + beta_v * xcn[m][nf][i];
        P[m * 16 + rq + i][cg] = f2bf(v);
      }
  }
  __syncthreads();

  // L6: Q = relu(P @ Wl1 + bl1)
  ZACC; computeL<256>(P, B0, B1, l15, kg, acc);
  EPI(Q, bvl1, 1);
  __syncthreads();

  // head: out[r] = Q[r,:] . Wl2 + bl2 (8 waves x 4 rows)
  {
    float bl2v = p.bl2[0];
    #pragma unroll
    for (int rr = 0; rr < 4; ++rr) {
      int r = wv * 4 + rr;
      bf16x4 q = *(const bf16x4*)&Q[r][lane * 4];
      float s = 0.f;
      #pragma unroll
      for (int u = 0; u < 4; ++u) s += bf2f((unsigned short)q[u]) * w2v[u];
      #pragma unroll
      for (int off = 32; off; off >>= 1) s += __shfl_down(s, off);
      if (lane == 0) p.out[m0 + r] = s + bl2v;
    }
  }
}

extern "C" void kernel_launch(void* const* d_in, const int* in_sizes, int n_in,
                              void* d_out, int out_size, void* d_ws, size_t ws_size,
                              hipStream_t stream) {
  char* ws = (char*)d_ws;
  KParams prm;
  prm.x     = (const float*)d_in[0];
  prm.adj_r = (const int*)d_in[1];
  prm.adj_c = (const int*)d_in[2];
  prm.tar   = (const int*)d_in[3];
  prm.beta  = (const float*)d_in[4];
  prm.W1    = (const float*)d_in[5];  prm.b1   = (const float*)d_in[6];
  prm.W2    = (const float*)d_in[7];  prm.b2   = (const float*)d_in[8];
  prm.W3    = (const float*)d_in[9];  prm.b3   = (const float*)d_in[10];
  prm.Wij1  = (const float*)d_in[11]; prm.bij1 = (const float*)d_in[12];
  prm.Wij2  = (const float*)d_in[13]; prm.bij2 = (const float*)d_in[14];
  prm.Wl1   = (const float*)d_in[15]; prm.bl1  = (const float*)d_in[16];
  prm.Wl2   = (const float*)d_in[17]; prm.bl2  = (const float*)d_in[18];
  prm.mask  = (unsigned*)ws;                                    // 12.8 MB
  prm.deg   = (int*)(ws + (size_t)MASK_WORDS * 4);              // 40 KB (contiguous: zeroed with mask)
  prm.csr   = (int*)(ws + (size_t)15 * 1024 * 1024);            // 5.12 MB
  prm.wts   = (unsigned short*)(ws + (size_t)21 * 1024 * 1024); // 656 KB
  prm.out   = (float*)d_out;

  void* args[] = { &prm };
  hipLaunchCooperativeKernel((const void*)fused_pipeline, dim3(GRID), dim3(TPB),
                             args, 0, stream);
}

// Round 7
// 75.260 us; speedup vs baseline: 1.9016x; 1.9016x over previous
//
#include <hip/hip_runtime.h>
#include <hip/hip_bf16.h>

#define N_NODES 10000
#define IN_CH 128
#define HID 256
#define E_TAR 8192
#define N_EDGES 320000
#define CSR_MAX 128
#define BM 32

typedef short bf16x8 __attribute__((ext_vector_type(8)));
typedef short bf16x4 __attribute__((ext_vector_type(4)));
typedef float f32x4 __attribute__((ext_vector_type(4)));

__device__ __forceinline__ unsigned short f2bf(float f) {
  union { float f; unsigned u; } v; v.f = f;
  unsigned r = v.u + 0x7fffu + ((v.u >> 16) & 1u);  // RNE
  return (unsigned short)(r >> 16);
}
__device__ __forceinline__ float bf2f(unsigned short h) {
  union { unsigned u; float f; } v; v.u = ((unsigned)h) << 16; return v.f;
}

// ---------- K1: weight transpose-convert (blocks 0..319) + zero deg (320..329) ----------
__global__ void prep_w(const float* __restrict__ W1, const float* __restrict__ W2,
                       const float* __restrict__ W3, const float* __restrict__ Wij1,
                       const float* __restrict__ Wij2, const float* __restrict__ Wl1,
                       unsigned short* __restrict__ wts, uint4* __restrict__ degz) {
  if (blockIdx.x >= 320) {
    int i = (blockIdx.x - 320) * 256 + threadIdx.x;
    if (i < (N_NODES + 3) / 4) degz[i] = (uint4){0u, 0u, 0u, 0u};
    return;
  }
  int bid = blockIdx.x;
  const float* W; unsigned short* O; int K, t;
  if      (bid <  32) { W = W1;   O = wts;          K = 128; t = bid; }
  else if (bid <  96) { W = W2;   O = wts + 32768;  K = 256; t = bid - 32; }
  else if (bid < 160) { W = W3;   O = wts + 98304;  K = 256; t = bid - 96; }
  else if (bid < 192) { W = Wij1; O = wts + 163840; K = 128; t = bid - 160; }
  else if (bid < 256) { W = Wij2; O = wts + 196608; K = 256; t = bid - 192; }
  else                { W = Wl1;  O = wts + 262144; K = 256; t = bid - 256; }
  int tpk = K / 32, tk = t % tpk, tn = t / tpk;
  __shared__ float tile[32][33];
  int tid = threadIdx.x;
  int c = tid & 31, r0 = tid >> 5;
  #pragma unroll
  for (int rr = 0; rr < 32; rr += 8)
    tile[r0 + rr][c] = W[(size_t)(tk * 32 + r0 + rr) * 256 + tn * 32 + c];
  __syncthreads();
  #pragma unroll
  for (int rr = 0; rr < 32; rr += 8)
    O[(size_t)(tn * 32 + r0 + rr) * K + tk * 32 + c] = f2bf(tile[c][r0 + rr]);
}

// ---------- K2: append-only CSR scatter (duplicates kept; dedup at intersect) ----------
__global__ void scatter_csr(const int* __restrict__ row, const int* __restrict__ col,
                            int* __restrict__ deg, int* __restrict__ csr) {
  int k = blockIdx.x * 256 + threadIdx.x;
  if (k < N_EDGES) {
    int r = row[k], c = col[k];
    int p = atomicAdd(&deg[r], 1);
    if (p < CSR_MAX) csr[(size_t)r * CSR_MAX + p] = c;
  }
}

// ---------- K3: CN intersect-gather + full MLP chain + head ----------
// MLP register discipline: NO arrays anywhere — named B regs (Bv0..Bv15),
// named accumulators, macro-expanded. (R6 postmortem: array-through-pointer
// B fragments were allocated in scratch -> VGPR_Count 72, 90% stall.)
__global__ __launch_bounds__(512, 2) void fused_all(
    const int* __restrict__ deg, const int* __restrict__ csr,
    const int* __restrict__ tar, const float* __restrict__ x,
    const unsigned short* __restrict__ wts,
    const float* __restrict__ b1, const float* __restrict__ b2, const float* __restrict__ b3,
    const float* __restrict__ bij1, const float* __restrict__ bij2, const float* __restrict__ bl1,
    const float* __restrict__ Wl2, const float* __restrict__ bl2,
    const float* __restrict__ betaPtr, float* __restrict__ out)
{
  __shared__ unsigned short P[BM][264];
  __shared__ unsigned short Q[BM][264];

  int m0 = blockIdx.x * BM;
  int tid = threadIdx.x;
  int lane = tid & 63, wv = tid >> 6;
  int wn = wv * 32;
  int l15 = lane & 15, kg = (lane >> 4) * 8, rq = (lane >> 4) * 4;

  bf16x8 Bv0, Bv1, Bv2, Bv3, Bv4, Bv5, Bv6, Bv7;
  bf16x8 Bv8, Bv9, Bv10, Bv11, Bv12, Bv13, Bv14, Bv15;
  f32x4 a00, a01, a10, a11;
  f32x4 x00, x01, x10, x11;   // xcn carried L3->L5

#define LB128(WT) { \
    const unsigned short* _p = (WT) + (size_t)(wn + l15) * 128 + kg; \
    const unsigned short* _q = (WT) + (size_t)(wn + 16 + l15) * 128 + kg; \
    Bv0 = *(const bf16x8*)_p;        Bv1 = *(const bf16x8*)(_p + 32); \
    Bv2 = *(const bf16x8*)(_p + 64); Bv3 = *(const bf16x8*)(_p + 96); \
    Bv8 = *(const bf16x8*)_q;        Bv9 = *(const bf16x8*)(_q + 32); \
    Bv10 = *(const bf16x8*)(_q + 64); Bv11 = *(const bf16x8*)(_q + 96); }

#define LB256(WT) { \
    const unsigned short* _p = (WT) + (size_t)(wn + l15) * 256 + kg; \
    const unsigned short* _q = (WT) + (size_t)(wn + 16 + l15) * 256 + kg; \
    Bv0 = *(const bf16x8*)_p;         Bv1 = *(const bf16x8*)(_p + 32); \
    Bv2 = *(const bf16x8*)(_p + 64);  Bv3 = *(const bf16x8*)(_p + 96); \
    Bv4 = *(const bf16x8*)(_p + 128); Bv5 = *(const bf16x8*)(_p + 160); \
    Bv6 = *(const bf16x8*)(_p + 192); Bv7 = *(const bf16x8*)(_p + 224); \
    Bv8 = *(const bf16x8*)_q;         Bv9 = *(const bf16x8*)(_q + 32); \
    Bv10 = *(const bf16x8*)(_q + 64); Bv11 = *(const bf16x8*)(_q + 96); \
    Bv12 = *(const bf16x8*)(_q + 128); Bv13 = *(const bf16x8*)(_q + 160); \
    Bv14 = *(const bf16x8*)(_q + 192); Bv15 = *(const bf16x8*)(_q + 224); }

#define ST(S, S8, AA) { \
    bf16x8 _a0 = *(const bf16x8*)&AA[l15][S * 32 + kg]; \
    bf16x8 _a1 = *(const bf16x8*)&AA[16 + l15][S * 32 + kg]; \
    a00 = __builtin_amdgcn_mfma_f32_16x16x32_bf16(_a0, Bv##S,  a00, 0, 0, 0); \
    a10 = __builtin_amdgcn_mfma_f32_16x16x32_bf16(_a1, Bv##S,  a10, 0, 0, 0); \
    a01 = __builtin_amdgcn_mfma_f32_16x16x32_bf16(_a0, Bv##S8, a01, 0, 0, 0); \
    a11 = __builtin_amdgcn_mfma_f32_16x16x32_bf16(_a1, Bv##S8, a11, 0, 0, 0); }

#define CL128(AA) ST(0, 8, AA) ST(1, 9, AA) ST(2, 10, AA) ST(3, 11, AA)
#define CL256(AA) CL128(AA) ST(4, 12, AA) ST(5, 13, AA) ST(6, 14, AA) ST(7, 15, AA)

#define ZA { a00 = (f32x4){0,0,0,0}; a01 = (f32x4){0,0,0,0}; \
             a10 = (f32x4){0,0,0,0}; a11 = (f32x4){0,0,0,0}; }

#define EPIW(DST, BS0, BS1, RELU) { \
    _Pragma("unroll") for (int i = 0; i < 4; ++i) { \
      float v0 = a00[i] + BS0, v1 = a10[i] + BS0; \
      float v2 = a01[i] + BS1, v3 = a11[i] + BS1; \
      if (RELU) { v0 = fmaxf(v0, 0.f); v1 = fmaxf(v1, 0.f); \
                  v2 = fmaxf(v2, 0.f); v3 = fmaxf(v3, 0.f); } \
      DST[rq + i][wn + l15]           = f2bf(v0); \
      DST[16 + rq + i][wn + l15]      = f2bf(v1); \
      DST[rq + i][wn + 16 + l15]      = f2bf(v2); \
      DST[16 + rq + i][wn + 16 + l15] = f2bf(v3); } }

  // L1 weights issued first; latency hides under gather + prefetches
  LB128(wts);

  // entry prefetches
  int row = tid >> 4, seg = tid & 15;
  int gi = tar[m0 + row], gj = tar[E_TAR + m0 + row];
  const float* xip = x + (size_t)gi * IN_CH + seg * 8;
  const float* xjp = x + (size_t)gj * IN_CH + seg * 8;
  f32x4 xi0 = *(const f32x4*)xip, xi1 = *(const f32x4*)(xip + 4);
  f32x4 xj0 = *(const f32x4*)xjp, xj1 = *(const f32x4*)(xjp + 4);
  float bv1_0   = b1[wn + l15],   bv1_1   = b1[wn + 16 + l15];
  float bv2_0   = b2[wn + l15],   bv2_1   = b2[wn + 16 + l15];
  float bv3_0   = b3[wn + l15],   bv3_1   = b3[wn + 16 + l15];
  float bvij1_0 = bij1[wn + l15], bvij1_1 = bij1[wn + 16 + l15];
  float bvij2_0 = bij2[wn + l15], bvij2_1 = bij2[wn + 16 + l15];
  float bvl1_0  = bl1[wn + l15],  bvl1_1  = bl1[wn + 16 + l15];
  float beta_v = betaPtr[0];
  f32x4 w2v = *(const f32x4*)&Wl2[lane * 4];

  // ---- CN gather via exact dedup'd list intersection (wave owns 4 edges) ----
  float g0[4] = {0.f, 0.f, 0.f, 0.f}, g1[4] = {0.f, 0.f, 0.f, 0.f};
  #pragma unroll
  for (int q = 0; q < 4; ++q) {
    int e = m0 + wv * 4 + q;
    int ti_ = tar[e], tj_ = tar[E_TAR + e];
    int di_ = min(deg[ti_], CSR_MAX), dj_ = min(deg[tj_], CSR_MAX);
    int a_ = (di_ <= dj_) ? ti_ : tj_;
    int b_ = (di_ <= dj_) ? tj_ : ti_;
    int da_ = min(di_, dj_), db_ = max(di_, dj_);
    const int* la = csr + (size_t)a_ * CSR_MAX;
    const int* lb = csr + (size_t)b_ * CSR_MAX;
    for (int ab = 0; ab < da_; ab += 64) {
      int t = ab + lane;
      int at = (t < da_) ? la[t] : -1;
      bool hit = false;                       // at ∈ listB ?
      for (int bb = 0; bb < db_; bb += 64) {
        int u = bb + lane;
        int bl = (u < db_) ? lb[u] : -2;
        int lim = db_ - bb; if (lim > 64) lim = 64;
        for (int j = 0; j < lim; ++j) {
          int bj = __shfl(bl, j);
          hit |= (at == bj);
        }
      }
      bool dup = false;                       // earlier occurrence in listA ?
      for (int pb = 0; pb <= ab; pb += 64) {
        int u = pb + lane;
        int av = (u < da_) ? la[u] : -3;
        int lim = da_ - pb; if (lim > 64) lim = 64;
        for (int k2 = 0; k2 < lim; ++k2) {
          int ak = __shfl(av, k2);
          dup |= ((pb + k2) < t && ak == at);
        }
      }
      bool good = (t < da_) && hit && !dup;
      unsigned long long bal = __ballot(good);
      while (bal) {
        int src = __ffsll(bal) - 1;
        bal &= bal - 1;
        int nb = __shfl(at, src);
        const float* xr = x + (size_t)nb * IN_CH;
        g0[q] += xr[lane];
        g1[q] += xr[lane + 64];
      }
    }
  }
  #pragma unroll
  for (int q = 0; q < 4; ++q) {
    int r = wv * 4 + q;
    P[r][lane]      = f2bf(g0[q]);
    P[r][64 + lane] = f2bf(g1[q]);
  }
  __syncthreads();

  // L1: Q = relu(P @ W1 + b1), K=128
  ZA; CL128(P); LB256(wts + 32768); EPIW(Q, bv1_0, bv1_1, true);
  __syncthreads();

  // L2: P = relu(Q @ W2 + b2), K=256
  ZA; CL256(Q); LB256(wts + 98304); EPIW(P, bv2_0, bv2_1, true);
  __syncthreads();

  // L3: xcn = P @ W3 + b3 (kept in regs)
  ZA; CL256(P); LB128(wts + 163840);
  #pragma unroll
  for (int i = 0; i < 4; ++i) {
    x00[i] = a00[i] + bv3_0; x10[i] = a10[i] + bv3_0;
    x01[i] = a01[i] + bv3_1; x11[i] = a11[i] + bv3_1;
  }
  __syncthreads();   // all P reads done before overwrite

  // xi*xj -> P
  {
    unsigned short tmp[8];
    #pragma unroll
    for (int u = 0; u < 4; ++u) {
      tmp[u]     = f2bf(xi0[u] * xj0[u]);
      tmp[4 + u] = f2bf(xi1[u] * xj1[u]);
    }
    *(bf16x8*)&P[row][seg * 8] = *(bf16x8*)tmp;
  }
  __syncthreads();

  // L4: Q = relu(P @ Wij1 + bij1), K=128
  ZA; CL128(P); LB256(wts + 196608); EPIW(Q, bvij1_0, bvij1_1, true);
  __syncthreads();

  // L5: P = (Q @ Wij2 + bij2) + beta*xcn
  ZA; CL256(Q); LB256(wts + 262144);
  #pragma unroll
  for (int i = 0; i < 4; ++i) {
    float v0 = a00[i] + bvij2_0 + beta_v * x00[i];
    float v1 = a10[i] + bvij2_0 + beta_v * x10[i];
    float v2 = a01[i] + bvij2_1 + beta_v * x01[i];
    float v3 = a11[i] + bvij2_1 + beta_v * x11[i];
    P[rq + i][wn + l15]           = f2bf(v0);
    P[16 + rq + i][wn + l15]      = f2bf(v1);
    P[rq + i][wn + 16 + l15]      = f2bf(v2);
    P[16 + rq + i][wn + 16 + l15] = f2bf(v3);
  }
  __syncthreads();

  // L6: Q = relu(P @ Wl1 + bl1)
  ZA; CL256(P); EPIW(Q, bvl1_0, bvl1_1, true);
  __syncthreads();

  // head: out[r] = Q[r,:] . Wl2 + bl2
  {
    float bl2v = bl2[0];
    #pragma unroll
    for (int rr = 0; rr < 4; ++rr) {
      int r = wv * 4 + rr;
      bf16x4 qv = *(const bf16x4*)&Q[r][lane * 4];
      float s = 0.f;
      #pragma unroll
      for (int u = 0; u < 4; ++u) s += bf2f((unsigned short)qv[u]) * w2v[u];
      #pragma unroll
      for (int off = 32; off; off >>= 1) s += __shfl_down(s, off);
      if (lane == 0) out[m0 + r] = s + bl2v;
    }
  }
}

extern "C" void kernel_launch(void* const* d_in, const int* in_sizes, int n_in,
                              void* d_out, int out_size, void* d_ws, size_t ws_size,
                              hipStream_t stream) {
  const float* x      = (const float*)d_in[0];
  const int*   adj_r  = (const int*)d_in[1];
  const int*   adj_c  = (const int*)d_in[2];
  const int*   tar    = (const int*)d_in[3];
  const float* beta   = (const float*)d_in[4];
  const float* W1     = (const float*)d_in[5];
  const float* b1     = (const float*)d_in[6];
  const float* W2     = (const float*)d_in[7];
  const float* b2     = (const float*)d_in[8];
  const float* W3     = (const float*)d_in[9];
  const float* b3     = (const float*)d_in[10];
  const float* Wij1   = (const float*)d_in[11];
  const float* bij1   = (const float*)d_in[12];
  const float* Wij2   = (const float*)d_in[13];
  const float* bij2   = (const float*)d_in[14];
  const float* Wl1    = (const float*)d_in[15];
  const float* bl1    = (const float*)d_in[16];
  const float* Wl2    = (const float*)d_in[17];
  const float* bl2    = (const float*)d_in[18];

  char* ws = (char*)d_ws;
  int*            deg = (int*)ws;                                  // 40 KB
  int*            csr = (int*)(ws + (size_t)1 * 1024 * 1024);      // 5.12 MB
  unsigned short* wts = (unsigned short*)(ws + (size_t)8 * 1024 * 1024); // 656 KB

  // K1: weight transpose (320 blocks) + deg zero (10 blocks)
  prep_w<<<330, 256, 0, stream>>>(W1, W2, W3, Wij1, Wij2, Wl1, wts, (uint4*)deg);
  // K2: append-only CSR
  scatter_csr<<<(N_EDGES + 255) / 256, 256, 0, stream>>>(adj_r, adj_c, deg, csr);
  // K3: gather + MLP + head
  fused_all<<<E_TAR / BM, 512, 0, stream>>>(deg, csr, tar, x, wts,
                                            b1, b2, b3, bij1, bij2, bl1,
                                            Wl2, bl2, beta, (float*)d_out);
}